// Round 1
// baseline (271.087 us; speedup 1.0000x reference)
//
#include <hip/hip_runtime.h>
#include <math.h>

#define NLEV 12
#define TSIZE (1u << 20)
#define PRIME_Y 2654435761u

__global__ __launch_bounds__(256) void hashsiren_kernel(
    const float* __restrict__ coords,
    const float* __restrict__ table,
    const float* __restrict__ W0, const float* __restrict__ b0,
    const float* __restrict__ W1, const float* __restrict__ b1,
    const float* __restrict__ W2, const float* __restrict__ b2,
    const float* __restrict__ W3, const float* __restrict__ b3,
    float* __restrict__ out, int N)
{
    __shared__ float sW0[384];
    __shared__ float sW1[256];
    __shared__ float sW2[256];
    __shared__ float sb0[16], sb1[16], sb2[16], sW3[16];
    __shared__ float sb3;

    const int t = threadIdx.x;
    // stage weights into LDS (uniform reads later broadcast for free)
    for (int i = t; i < 384; i += 256) sW0[i] = W0[i];
    if (t < 256) { sW1[t] = W1[t]; sW2[t] = W2[t]; }
    if (t < 16) { sb0[t] = b0[t]; sb1[t] = b1[t]; sb2[t] = b2[t]; sW3[t] = W3[t]; }
    if (t == 0) sb3 = b3[0];
    __syncthreads();

    const int idx = blockIdx.x * 256 + t;
    if (idx >= N) return;

    const float2 c = reinterpret_cast<const float2*>(coords)[idx];

    float enc[24];
    #pragma unroll
    for (int lvl = 0; lvl < NLEV; ++lvl) {
        const int res = 16 << lvl;                 // floor(16 * 2^lvl), exact
        const float px = c.x * (float)res;
        const float py = c.y * (float)res;
        const float fx = floorf(px), fy = floorf(py);
        const float wx = px - fx, wy = py - fy;
        const int ix = (int)fx, iy = (int)fy;
        const float* __restrict__ tl = table + (size_t)lvl * (size_t)TSIZE * 2u;

        float2 v00, v10, v01, v11;
        if (lvl <= 5) {
            // dense: (res+1)^2 <= TSIZE
            const int stride = res + 1;
            const int base = ix + iy * stride;
            v00 = *reinterpret_cast<const float2*>(tl + 2 * (size_t)(base));
            v10 = *reinterpret_cast<const float2*>(tl + 2 * (size_t)(base + 1));
            v01 = *reinterpret_cast<const float2*>(tl + 2 * (size_t)(base + stride));
            v11 = *reinterpret_cast<const float2*>(tl + 2 * (size_t)(base + stride + 1));
        } else {
            const unsigned ux = (unsigned)ix, uy = (unsigned)iy;
            const unsigned hy0 = uy * PRIME_Y;
            const unsigned hy1 = (uy + 1u) * PRIME_Y;
            const unsigned h00 = (ux ^ hy0) & (TSIZE - 1u);
            const unsigned h10 = ((ux + 1u) ^ hy0) & (TSIZE - 1u);
            const unsigned h01 = (ux ^ hy1) & (TSIZE - 1u);
            const unsigned h11 = ((ux + 1u) ^ hy1) & (TSIZE - 1u);
            v00 = *reinterpret_cast<const float2*>(tl + 2 * (size_t)h00);
            v10 = *reinterpret_cast<const float2*>(tl + 2 * (size_t)h10);
            v01 = *reinterpret_cast<const float2*>(tl + 2 * (size_t)h01);
            v11 = *reinterpret_cast<const float2*>(tl + 2 * (size_t)h11);
        }
        const float w00 = (1.0f - wx) * (1.0f - wy);
        const float w10 = wx * (1.0f - wy);
        const float w01 = (1.0f - wx) * wy;
        const float w11 = wx * wy;
        enc[2 * lvl]     = v00.x * w00 + v10.x * w10 + v01.x * w01 + v11.x * w11;
        enc[2 * lvl + 1] = v00.y * w00 + v10.y * w10 + v01.y * w01 + v11.y * w11;
    }

    // ---- MLP: sin(300*(enc@W0+b0)) -> sin(h@W1+b1) -> sin(h@W2+b2) -> h@W3+b3
    float h0[16];
    #pragma unroll
    for (int j = 0; j < 16; ++j) {
        float a = sb0[j];
        #pragma unroll
        for (int k = 0; k < 24; ++k) a += enc[k] * sW0[k * 16 + j];
        h0[j] = sinf(300.0f * a);
    }
    float h1[16];
    #pragma unroll
    for (int j = 0; j < 16; ++j) {
        float a = sb1[j];
        #pragma unroll
        for (int k = 0; k < 16; ++k) a += h0[k] * sW1[k * 16 + j];
        h1[j] = sinf(a);
    }
    float h2[16];
    #pragma unroll
    for (int j = 0; j < 16; ++j) {
        float a = sb2[j];
        #pragma unroll
        for (int k = 0; k < 16; ++k) a += h1[k] * sW2[k * 16 + j];
        h2[j] = sinf(a);
    }
    float o = sb3;
    #pragma unroll
    for (int k = 0; k < 16; ++k) o += h2[k] * sW3[k];
    out[idx] = o;
}

extern "C" void kernel_launch(void* const* d_in, const int* in_sizes, int n_in,
                              void* d_out, int out_size, void* d_ws, size_t ws_size,
                              hipStream_t stream) {
    const float* coords = (const float*)d_in[0];
    const float* table  = (const float*)d_in[1];
    const float* W0 = (const float*)d_in[2];
    const float* b0 = (const float*)d_in[3];
    const float* W1 = (const float*)d_in[4];
    const float* b1 = (const float*)d_in[5];
    const float* W2 = (const float*)d_in[6];
    const float* b2 = (const float*)d_in[7];
    const float* W3 = (const float*)d_in[8];
    const float* b3 = (const float*)d_in[9];
    float* out = (float*)d_out;

    const int N = in_sizes[0] / 2;  // coords is [N,2]
    const int block = 256;
    const int grid = (N + block - 1) / block;
    hashsiren_kernel<<<grid, block, 0, stream>>>(coords, table, W0, b0, W1, b1,
                                                 W2, b2, W3, b3, out, N);
}